// Round 1
// baseline (159.943 us; speedup 1.0000x reference)
//
#include <hip/hip_runtime.h>
#include <math.h>

#define NSHOT 5
#define WAY 32
#define DIM 640
#define NQ 4096
#define RNEAR 10

// ---- workspace layout (float offsets) ----
constexpr int OFF_QSUM    = 0;         // 640
constexpr int OFF_PROTOS  = 640;       // 32*640
constexpr int OFF_ALLMEAN = 21120;     // 640
constexpr int OFF_C       = 21760;     // 32
constexpr int OFF_XVEC    = 21792;     // 32*640 (proto_p, then reused conceptually)
constexpr int OFF_G       = 42272;     // 32*4096
constexpr int OFF_DIS     = 173344;    // 32*4096
constexpr int OFF_S       = 304416;    // 32
constexpr int OFF_U       = 304448;    // 32
constexpr int OFF_NID     = 304480;    // 32*10
constexpr int OFF_IW      = 304800;    // 32*10
constexpr int OFF_ONW     = 305120;    // 32
constexpr int OFF_TP      = 305152;    // 32*640 (test_proto)
constexpr int OFF_NIDX    = 325632;    // 32*10 ints
constexpr int OFF_Q2D     = 325952;    // double[4096]  (even float offset -> 8B aligned)
constexpr int OFF_X2D     = 334144;    // double[32]

__device__ __forceinline__ double wave_sum_d(double v) {
#pragma unroll
  for (int o = 32; o > 0; o >>= 1) v += __shfl_down(v, o, 64);
  return v;
}

// full Mobius/Poincare distance given xdotq = x . q_raw, u2 = ||x||^2, q2 = ||q_raw||^2
__device__ __forceinline__ double dist_hyp(double c, double xdotq, double u2, double q2) {
  const double EPSd = 1e-5;
  double sc = sqrt(c);
  double nq = sqrt(q2);
  double nf = fmax(nq, EPSd);
  double th = tanh(sc * nf);
  double al = th / (sc * nf);            // expmap0 scale for the query
  double ny = fmax(al * nq, EPSd);
  double mx = 0.999 / sc;
  if (ny > mx) al *= mx / ny;            // projection clip
  double y2 = al * al * q2;
  double uy = -al * xdotq;
  double A = 1.0 + 2.0 * c * uy + c * y2;
  double B = 1.0 - c * u2;
  double den = fmax(1.0 + 2.0 * c * uy + c * c * u2 * y2, EPSd);
  double num2 = fmax(A * A * u2 + 2.0 * A * B * uy + B * B * y2, 0.0);
  double n = sqrt(num2) / den;
  double arg = sc * n;
  const double CLIP = (double)(1.0f - 1e-5f);  // match f32 clip constant
  arg = fmin(fmax(arg, 0.0), CLIP);
  return (1.0 / sc) * log((1.0 + arg) / (1.0 - arg));  // (2/sc)*atanh(arg)
}

__global__ void k_zero(float* ws) {
  int i = blockIdx.x * blockDim.x + threadIdx.x;
  if (i < 640) ws[OFF_QSUM + i] = 0.0f;
  for (int j = i; j < WAY * NQ; j += gridDim.x * blockDim.x) ws[OFF_G + j] = 0.0f;
}

// per-query squared norms (double)
__global__ __launch_bounds__(256) void k_q2(const float* __restrict__ Qm, float* ws) {
  double* q2d = (double*)(ws + OFF_Q2D);
  int wid = threadIdx.x >> 6, lane = threadIdx.x & 63;
  int row = blockIdx.x * 4 + wid;
  const float* r = Qm + (size_t)row * DIM;
  double s = 0.0;
  for (int j = lane; j < DIM; j += 64) { double v = r[j]; s += v * v; }
  s = wave_sum_d(s);
  if (lane == 0) q2d[row] = s;
}

// column sums of data_query
__global__ void k_qsum(const float* __restrict__ Qm, float* ws) {
  __shared__ float red[4][64];
  int col = blockIdx.x * 64 + threadIdx.x;
  int r0 = blockIdx.y * 512 + threadIdx.y * 128;
  float s = 0.f;
  for (int r = 0; r < 128; ++r) s += Qm[(size_t)(r0 + r) * DIM + col];
  red[threadIdx.y][threadIdx.x] = s;
  __syncthreads();
  if (threadIdx.y == 0) {
    float tot = red[0][threadIdx.x] + red[1][threadIdx.x] + red[2][threadIdx.x] + red[3][threadIdx.x];
    atomicAdd(&ws[OFF_QSUM + col], tot);
  }
}

__global__ void k_protos(const float* __restrict__ shot, float* ws) {
  int i = blockIdx.x * blockDim.x + threadIdx.x;
  if (i >= WAY * DIM) return;
  int w = i / DIM, d = i - w * DIM;
  float s = 0.f;
#pragma unroll
  for (int s5 = 0; s5 < NSHOT; ++s5) s += shot[(size_t)(s5 * WAY + w) * DIM + d];
  ws[OFF_PROTOS + i] = s * 0.2f;
}

__global__ void k_allmean(float* ws) {
  int d = threadIdx.x;
  if (d >= DIM) return;
  double s = ws[OFF_QSUM + d];
  for (int w = 0; w < WAY; ++w) s += 5.0 * (double)ws[OFF_PROTOS + w * DIM + d];
  ws[OFF_ALLMEAN + d] = (float)(s / 4256.0);
}

// controller MLP -> c[w], proto_p (=beta*protos) and ||proto_p||^2
__global__ __launch_bounds__(128) void k_ctrl(const float* __restrict__ W1, const float* __restrict__ b1,
                                              const float* __restrict__ W2, const float* __restrict__ b2,
                                              const float* __restrict__ W3, const float* __restrict__ b3,
                                              float* ws) {
  __shared__ float pr[DIM], am[DIM];
  __shared__ float h1s[128], h2s[64], lg[5];
  __shared__ double redd[2];
  __shared__ double sBeta;
  int w = blockIdx.x, t = threadIdx.x;
  double ps = 0.0;
  for (int d = t; d < DIM; d += 128) {
    float v = ws[OFF_PROTOS + w * DIM + d];
    pr[d] = v; ps += (double)v * v;
    am[d] = ws[OFF_ALLMEAN + d];
  }
  ps = wave_sum_d(ps);
  int lane = t & 63, wid = t >> 6;
  if (lane == 0) redd[wid] = ps;
  __syncthreads();
  float acc = b1[t];
  for (int k = 0; k < DIM; ++k) acc = fmaf(pr[k], W1[k * 128 + t], acc);
  for (int k = 0; k < DIM; ++k) acc = fmaf(am[k], W1[(DIM + k) * 128 + t], acc);
  h1s[t] = fmaxf(acc, 0.f);
  __syncthreads();
  if (t < 64) {
    float a = b2[t];
    for (int k = 0; k < 128; ++k) a = fmaf(h1s[k], W2[k * 64 + t], a);
    h2s[t] = fmaxf(a, 0.f);
  }
  __syncthreads();
  if (t < 5) {
    float a = b3[t];
    for (int k = 0; k < 64; ++k) a = fmaf(h2s[k], W3[k * 5 + t], a);
    lg[t] = a;
  }
  __syncthreads();
  if (t == 0) {
    double p2 = redd[0] + redd[1];
    double m = lg[0];
    for (int i = 1; i < 5; ++i) m = fmax(m, (double)lg[i]);
    double se = 0.0, cv = 0.0;
    for (int i = 0; i < 5; ++i) { double e = exp((double)lg[i] - m); se += e; cv += e * 0.2 * (double)(i + 1); }
    double c = cv / se;
    ws[OFF_C + w] = (float)c;
    double sc = sqrt(c);
    double ntrue = sqrt(p2);
    double nf = fmax(ntrue, 1e-5);
    double th = tanh(sc * nf);
    double s0 = th / (sc * nf);
    double ny = fmax(s0 * ntrue, 1e-5);
    double mx = 0.999 / sc;
    if (ny > mx) s0 *= mx / ny;
    sBeta = s0;
    ((double*)(ws + OFF_X2D))[w] = s0 * s0 * p2;
  }
  __syncthreads();
  float beta = (float)sBeta;
  for (int d = t; d < DIM; d += 128) ws[OFF_XVEC + w * DIM + d] = beta * pr[d];
}

// split-K GEMM: G[w][q] += X[w]·Qm[q] over a 64-dim K chunk (grid: 32 q-tiles x 10 k-tiles)
__global__ __launch_bounds__(256) void k_gemm(const float* __restrict__ X, const float* __restrict__ Qm,
                                              float* __restrict__ G) {
  __shared__ float qs[64][132];
  __shared__ float xs[64][36];
  int q0 = blockIdx.x * 128, k0 = blockIdx.y * 64;
  int t = threadIdx.x;
  {
    int kk = t & 15, qb = t >> 4;
#pragma unroll
    for (int p = 0; p < 8; ++p) {
      int q = p * 16 + qb;
      const float4 v = *(const float4*)(Qm + (size_t)(q0 + q) * DIM + k0 + kk * 4);
      qs[kk * 4 + 0][q] = v.x; qs[kk * 4 + 1][q] = v.y; qs[kk * 4 + 2][q] = v.z; qs[kk * 4 + 3][q] = v.w;
    }
#pragma unroll
    for (int p = 0; p < 2; ++p) {
      int fi = p * 256 + t;
      int xw = fi >> 4, kk2 = fi & 15;
      const float4 v = *(const float4*)(X + (size_t)xw * DIM + k0 + kk2 * 4);
      xs[kk2 * 4 + 0][xw] = v.x; xs[kk2 * 4 + 1][xw] = v.y; xs[kk2 * 4 + 2][xw] = v.z; xs[kk2 * 4 + 3][xw] = v.w;
    }
  }
  __syncthreads();
  int qg = t & 31, wg = t >> 5;
  float acc[4][4] = {};
#pragma unroll 8
  for (int k = 0; k < 64; ++k) {
    float4 qv = *(const float4*)&qs[k][qg * 4];
    float4 xv = *(const float4*)&xs[k][wg * 4];
    acc[0][0] = fmaf(xv.x, qv.x, acc[0][0]); acc[0][1] = fmaf(xv.x, qv.y, acc[0][1]);
    acc[0][2] = fmaf(xv.x, qv.z, acc[0][2]); acc[0][3] = fmaf(xv.x, qv.w, acc[0][3]);
    acc[1][0] = fmaf(xv.y, qv.x, acc[1][0]); acc[1][1] = fmaf(xv.y, qv.y, acc[1][1]);
    acc[1][2] = fmaf(xv.y, qv.z, acc[1][2]); acc[1][3] = fmaf(xv.y, qv.w, acc[1][3]);
    acc[2][0] = fmaf(xv.z, qv.x, acc[2][0]); acc[2][1] = fmaf(xv.z, qv.y, acc[2][1]);
    acc[2][2] = fmaf(xv.z, qv.z, acc[2][2]); acc[2][3] = fmaf(xv.z, qv.w, acc[2][3]);
    acc[3][0] = fmaf(xv.w, qv.x, acc[3][0]); acc[3][1] = fmaf(xv.w, qv.y, acc[3][1]);
    acc[3][2] = fmaf(xv.w, qv.z, acc[3][2]); acc[3][3] = fmaf(xv.w, qv.w, acc[3][3]);
  }
  int wb = wg * 4, qb2 = q0 + qg * 4;
#pragma unroll
  for (int i = 0; i < 4; ++i)
#pragma unroll
    for (int j = 0; j < 4; ++j)
      atomicAdd(&G[(size_t)(wb + i) * NQ + qb2 + j], acc[i][j]);
}

__global__ __launch_bounds__(256) void k_epi1(float* ws) {
  const double* q2d = (const double*)(ws + OFF_Q2D);
  const double* x2d = (const double*)(ws + OFF_X2D);
  int gid = blockIdx.x * 256 + threadIdx.x;
  if (gid >= WAY * NQ) return;
  int w = gid >> 12, q = gid & (NQ - 1);
  double c = (double)ws[OFF_C + w];
  double d = dist_hyp(c, (double)ws[OFF_G + gid], x2d[w], q2d[q]);
  ws[OFF_DIS + gid] = (float)d;
}

// per-way: row sum S, first-10-raw-col sum U, stable top-10 (value, then index)
__global__ __launch_bounds__(256) void k_topk(float* ws, int* nidx) {
  __shared__ double sredS[4], sredU[4];
  __shared__ float wv[4]; __shared__ int wi[4];
  __shared__ int swi;
  int w = blockIdx.x, t = threadIdx.x;
  int lane = t & 63, wid = t >> 6;
  float v[16]; bool tk[16];
  double s = 0.0, u = 0.0;
#pragma unroll
  for (int i = 0; i < 16; ++i) {
    int q = i * 256 + t;
    float vv = ws[OFF_DIS + w * NQ + q];
    v[i] = vv; tk[i] = false;
    s += vv;
    if (i == 0 && t < RNEAR) u += vv;
  }
  s = wave_sum_d(s);
  u = wave_sum_d(u);
  if (lane == 0) { sredS[wid] = s; sredU[wid] = u; }
  __syncthreads();
  if (t == 0) {
    ws[OFF_S + w] = (float)(sredS[0] + sredS[1] + sredS[2] + sredS[3]);
    ws[OFF_U + w] = (float)(sredU[0] + sredU[1] + sredU[2] + sredU[3]);
  }
  for (int r = 0; r < RNEAR; ++r) {
    float lv = INFINITY; int li = 0x7fffffff;
#pragma unroll
    for (int i = 0; i < 16; ++i) {
      if (!tk[i]) {
        float vv = v[i]; int qq = i * 256 + t;
        if (vv < lv || (vv == lv && qq < li)) { lv = vv; li = qq; }
      }
    }
#pragma unroll
    for (int o = 32; o > 0; o >>= 1) {
      float ov = __shfl_down(lv, o, 64);
      int oi = __shfl_down(li, o, 64);
      if (ov < lv || (ov == lv && oi < li)) { lv = ov; li = oi; }
    }
    if (lane == 0) { wv[wid] = lv; wi[wid] = li; }
    __syncthreads();
    if (t == 0) {
      float bv = wv[0]; int bi = wi[0];
      for (int k = 1; k < 4; ++k)
        if (wv[k] < bv || (wv[k] == bv && wi[k] < bi)) { bv = wv[k]; bi = wi[k]; }
      ws[OFF_NID + w * RNEAR + r] = bv;
      nidx[w * RNEAR + r] = bi;
      swi = bi;
    }
    __syncthreads();
    if ((swi & 255) == t) tk[swi >> 8] = true;
    __syncthreads();
  }
}

// all the small per-way stats + refine MLP -> i_w, onw
__global__ __launch_bounds__(384) void k_refine(const float* __restrict__ Wr1, const float* __restrict__ br1,
                                                const float* __restrict__ Wr2, const float* __restrict__ br2,
                                                float* ws, const int* __restrict__ nidx) {
  __shared__ float rr[WAY][22];
  __shared__ float pcs[WAY][RNEAR];
  __shared__ float Ssh[WAY], Tsh[WAY];
  __shared__ float hr[WAY][RNEAR];
  int t = threadIdx.x;
  if (t < WAY * RNEAR) {
    int w = t / RNEAR, j = t - w * RNEAR;
    int q = nidx[t];
    double cs = 0.0, pc = 0.0;
    for (int w2 = 0; w2 < WAY; ++w2) {
      float dv = ws[OFF_DIS + w2 * NQ + q];
      cs += dv;
      if (w2 < w) pc += dv;
    }
    float nv = ws[OFF_NID + t];
    rr[w][j] = nv;                                   // n_i_d
    rr[w][RNEAR + j] = (float)((cs - nv) / (WAY - 1)); // n_o_d
    pcs[w][j] = (float)pc;
  }
  if (t < WAY) { Ssh[t] = ws[OFF_S + t]; Tsh[t] = Ssh[t] - ws[OFF_U + t]; }
  __syncthreads();
  if (t < WAY) {
    int w = t;
    double sn = 0.0;
    for (int j = 0; j < RNEAR; ++j) sn += rr[w][j];
    double oi = ((double)Ssh[w] - sn) / (double)(NQ - RNEAR);
    double pref = 0.0; for (int j = 0; j < w; ++j) pref += Ssh[j];
    double suf = 0.0; for (int j = w + 1; j < WAY; ++j) suf += Tsh[j];
    double spc = 0.0; for (int j = 0; j < RNEAR; ++j) spc += pcs[w][j];
    double ood = (pref - spc + suf) / ((double)(WAY - 1) * (double)(NQ - RNEAR));
    rr[w][20] = (float)oi;
    rr[w][21] = (float)ood;
  }
  __syncthreads();
  if (t < WAY * RNEAR) {
    int w = t / RNEAR, r = t - w * RNEAR;
    float a = br1[r];
    for (int k = 0; k < 22; ++k) a = fmaf(rr[w][k], Wr1[k * RNEAR + r], a);
    hr[w][r] = fmaxf(a, 0.f);
  }
  __syncthreads();
  if (t < WAY) {
    int w = t;
    double o[11];
    for (int r2 = 0; r2 < 11; ++r2) {
      float a = br2[r2];
      for (int k = 0; k < RNEAR; ++k) a = fmaf(hr[w][k], Wr2[k * 11 + r2], a);
      o[r2] = a;
    }
    double m = o[0]; for (int i = 1; i < RNEAR; ++i) m = fmax(m, o[i]);
    double se = 0.0; double e[RNEAR];
    for (int i = 0; i < RNEAR; ++i) { e[i] = exp(o[i] - m); se += e[i]; }
    for (int i = 0; i < RNEAR; ++i) ws[OFF_IW + w * RNEAR + i] = (float)(e[i] / se);
    ws[OFF_ONW + w] = (float)(1.0 / (1.0 + exp(-o[10])));
  }
}

// tmp = protos*onw + wdq*(1-onw); test_proto = expmap0(tmp); also zero G for GEMM2
__global__ __launch_bounds__(256) void k_tmp(const float* __restrict__ Qm, float* ws, const int* __restrict__ nidx) {
  __shared__ float iw_s[RNEAR];
  __shared__ int qidx[RNEAR];
  __shared__ float tmps[DIM];
  __shared__ double sred[4];
  __shared__ double gsh;
  int w = blockIdx.x, t = threadIdx.x;
  if (t < RNEAR) { iw_s[t] = ws[OFF_IW + w * RNEAR + t]; qidx[t] = nidx[w * RNEAR + t]; }
  __syncthreads();
  float onwv = ws[OFF_ONW + w];
  double ls = 0.0;
  for (int d = t; d < DIM; d += 256) {
    float wd = 0.f;
#pragma unroll
    for (int j = 0; j < RNEAR; ++j) wd = fmaf(Qm[(size_t)qidx[j] * DIM + d], iw_s[j], wd);
    float a = ws[OFF_PROTOS + w * DIM + d] * onwv + wd * (1.f - onwv);
    tmps[d] = a;
    ls += (double)a * a;
  }
  ls = wave_sum_d(ls);
  int lane = t & 63, wid = t >> 6;
  if (lane == 0) sred[wid] = ls;
  __syncthreads();
  if (t == 0) {
    double p2 = sred[0] + sred[1] + sred[2] + sred[3];
    double c = (double)ws[OFF_C + w];
    double sc = sqrt(c);
    double ntrue = sqrt(p2);
    double nf = fmax(ntrue, 1e-5);
    double th = tanh(sc * nf);
    double s0 = th / (sc * nf);
    double ny = fmax(s0 * ntrue, 1e-5);
    double mx = 0.999 / sc;
    if (ny > mx) s0 *= mx / ny;
    gsh = s0;
    ((double*)(ws + OFF_X2D))[w] = s0 * s0 * p2;
  }
  __syncthreads();
  float g = (float)gsh;
  for (int d = t; d < DIM; d += 256) ws[OFF_TP + w * DIM + d] = g * tmps[d];
  int gt = w * 256 + t;
  for (int j = gt; j < WAY * NQ; j += WAY * 256) ws[OFF_G + j] = 0.0f;
}

// final distances -> out[q][w] = -d/16, via LDS transpose for coalesced writes
__global__ __launch_bounds__(256) void k_epi2(float* ws, float* __restrict__ out) {
  __shared__ float ot[64][33];
  const double* q2d = (const double*)(ws + OFF_Q2D);
  const double* x2d = (const double*)(ws + OFF_X2D);
  int qb = blockIdx.x * 64, t = threadIdx.x;
  int w = t >> 3, q80 = (t & 7) * 8;
  double c = (double)ws[OFF_C + w];
  double u2 = x2d[w];
  for (int j = 0; j < 8; ++j) {
    int qq = q80 + j, q = qb + qq;
    double g = (double)ws[OFF_G + (size_t)w * NQ + q];
    double d = dist_hyp(c, g, u2, q2d[q]);
    ot[qq][w] = (float)(-d / 16.0);
  }
  __syncthreads();
  for (int j = 0; j < 8; ++j) {
    int l = t * 8 + j;
    int qq = l >> 5, w2 = l & 31;
    out[(size_t)(qb + qq) * WAY + w2] = ot[qq][w2];
  }
}

extern "C" void kernel_launch(void* const* d_in, const int* in_sizes, int n_in,
                              void* d_out, int out_size, void* d_ws, size_t ws_size,
                              hipStream_t stream) {
  (void)in_sizes; (void)n_in; (void)out_size; (void)ws_size;
  const float* shot = (const float*)d_in[0];
  const float* qry  = (const float*)d_in[1];
  const float* W1   = (const float*)d_in[2];
  const float* b1   = (const float*)d_in[3];
  const float* W2   = (const float*)d_in[4];
  const float* b2   = (const float*)d_in[5];
  const float* W3   = (const float*)d_in[6];
  const float* b3   = (const float*)d_in[7];
  const float* Wr1  = (const float*)d_in[8];
  const float* br1  = (const float*)d_in[9];
  const float* Wr2  = (const float*)d_in[10];
  const float* br2  = (const float*)d_in[11];
  float* ws = (float*)d_ws;
  float* out = (float*)d_out;
  int* nidx = (int*)(ws + OFF_NIDX);

  hipLaunchKernelGGL(k_zero,   dim3(516), dim3(256), 0, stream, ws);
  hipLaunchKernelGGL(k_q2,     dim3(1024), dim3(256), 0, stream, qry, ws);
  hipLaunchKernelGGL(k_qsum,   dim3(10, 8), dim3(64, 4), 0, stream, qry, ws);
  hipLaunchKernelGGL(k_protos, dim3(80), dim3(256), 0, stream, shot, ws);
  hipLaunchKernelGGL(k_allmean, dim3(1), dim3(640), 0, stream, ws);
  hipLaunchKernelGGL(k_ctrl,   dim3(32), dim3(128), 0, stream, W1, b1, W2, b2, W3, b3, ws);
  hipLaunchKernelGGL(k_gemm,   dim3(32, 10), dim3(256), 0, stream, ws + OFF_XVEC, qry, ws + OFF_G);
  hipLaunchKernelGGL(k_epi1,   dim3(512), dim3(256), 0, stream, ws);
  hipLaunchKernelGGL(k_topk,   dim3(32), dim3(256), 0, stream, ws, nidx);
  hipLaunchKernelGGL(k_refine, dim3(1), dim3(384), 0, stream, Wr1, br1, Wr2, br2, ws, nidx);
  hipLaunchKernelGGL(k_tmp,    dim3(32), dim3(256), 0, stream, qry, ws, nidx);
  hipLaunchKernelGGL(k_gemm,   dim3(32, 10), dim3(256), 0, stream, ws + OFF_TP, qry, ws + OFF_G);
  hipLaunchKernelGGL(k_epi2,   dim3(64), dim3(256), 0, stream, ws, out);
}

// Round 3
// 138.677 us; speedup vs baseline: 1.1534x; 1.1534x over previous
//
#include <hip/hip_runtime.h>
#include <math.h>

#define NSHOT 5
#define WAY 32
#define DIM 640
#define NQ 4096
#define RNEAR 10

// ---- workspace layout (float offsets) ----
constexpr int OFF_QSUM    = 0;         // 640
constexpr int OFF_PROTOS  = 640;       // 32*640
constexpr int OFF_ALLMEAN = 21120;     // 640 (unused now, kept for layout stability)
constexpr int OFF_C       = 21760;     // 32
constexpr int OFF_XVEC    = 21792;     // 32*640 (proto_p)
constexpr int OFF_G       = 42272;     // 32*4096
constexpr int OFF_DIS     = 173344;    // 32*4096
constexpr int OFF_S       = 304416;    // 32
constexpr int OFF_U       = 304448;    // 32
constexpr int OFF_NID     = 304480;    // 32*10
constexpr int OFF_IW      = 304800;    // 32*10
constexpr int OFF_ONW     = 305120;    // 32
constexpr int OFF_TP      = 305152;    // 32*640 (test_proto)
constexpr int OFF_NIDX    = 325632;    // 32*10 ints
constexpr int OFF_Q2D     = 325952;    // double[4096]
constexpr int OFF_X2D     = 334144;    // double[32]

__device__ __forceinline__ double wave_sum_d(double v) {
#pragma unroll
  for (int o = 32; o > 0; o >>= 1) v += __shfl_down(v, o, 64);
  return v;
}

__device__ __forceinline__ double dist_hyp(double c, double xdotq, double u2, double q2) {
  const double EPSd = 1e-5;
  double sc = sqrt(c);
  double nq = sqrt(q2);
  double nf = fmax(nq, EPSd);
  double th = tanh(sc * nf);
  double al = th / (sc * nf);
  double ny = fmax(al * nq, EPSd);
  double mx = 0.999 / sc;
  if (ny > mx) al *= mx / ny;
  double y2 = al * al * q2;
  double uy = -al * xdotq;
  double A = 1.0 + 2.0 * c * uy + c * y2;
  double B = 1.0 - c * u2;
  double den = fmax(1.0 + 2.0 * c * uy + c * c * u2 * y2, EPSd);
  double num2 = fmax(A * A * u2 + 2.0 * A * B * uy + B * B * y2, 0.0);
  double n = sqrt(num2) / den;
  double arg = sc * n;
  const double CLIP = (double)(1.0f - 1e-5f);
  arg = fmin(fmax(arg, 0.0), CLIP);
  return (1.0 / sc) * log((1.0 + arg) / (1.0 - arg));
}

// per-query squared norms (double) + zero G for gemm1 atomics
__global__ __launch_bounds__(256) void k_q2(const float* __restrict__ Qm, float* ws) {
  double* q2d = (double*)(ws + OFF_Q2D);
  int wid = threadIdx.x >> 6, lane = threadIdx.x & 63;
  int row = blockIdx.x * 4 + wid;
  const float* r = Qm + (size_t)row * DIM;
  double s = 0.0;
  for (int j = lane; j < DIM; j += 64) { double v = r[j]; s += v * v; }
  s = wave_sum_d(s);
  if (lane == 0) q2d[row] = s;
  int gid = blockIdx.x * 256 + threadIdx.x;
  if (gid < WAY * NQ) ws[OFF_G + gid] = 0.0f;
}

// column sums of data_query: grid (10, 32), block 256 = 64 cols x 4 row-groups
__global__ void k_qsum(const float* __restrict__ Qm, float* ws) {
  __shared__ float red[4][64];
  int col = blockIdx.x * 64 + threadIdx.x;
  int r0 = blockIdx.y * 128 + threadIdx.y * 32;
  float s = 0.f;
  for (int r = 0; r < 32; ++r) s += Qm[(size_t)(r0 + r) * DIM + col];
  red[threadIdx.y][threadIdx.x] = s;
  __syncthreads();
  if (threadIdx.y == 0) {
    float tot = red[0][threadIdx.x] + red[1][threadIdx.x] + red[2][threadIdx.x] + red[3][threadIdx.x];
    atomicAdd(&ws[OFF_QSUM + col], tot);
  }
}

__global__ void k_zeroqs(float* ws) {
  int i = blockIdx.x * blockDim.x + threadIdx.x;
  if (i < 640) ws[OFF_QSUM + i] = 0.0f;
}

__global__ void k_protos(const float* __restrict__ shot, float* ws) {
  int i = blockIdx.x * blockDim.x + threadIdx.x;
  if (i >= WAY * DIM) return;
  int w = i / DIM, d = i - w * DIM;
  float s = 0.f;
#pragma unroll
  for (int s5 = 0; s5 < NSHOT; ++s5) s += shot[(size_t)(s5 * WAY + w) * DIM + d];
  ws[OFF_PROTOS + i] = s * 0.2f;
}

// controller MLP, split-K, 512 threads; allmean computed inline per block
__global__ __launch_bounds__(512) void k_ctrl(const float* __restrict__ W1, const float* __restrict__ b1,
                                              const float* __restrict__ W2, const float* __restrict__ b2,
                                              const float* __restrict__ W3, const float* __restrict__ b3,
                                              float* ws) {
  __shared__ float pr[DIM], am[DIM];
  __shared__ float h1p[4][128], h1s[128];
  __shared__ float h2p[8][64], h2s[64];
  __shared__ float lg[5];
  __shared__ double redd[8];
  __shared__ double sBeta;
  int w = blockIdx.x, t = threadIdx.x;
  double ps = 0.0;
  for (int d = t; d < DIM; d += 512) {
    float v = ws[OFF_PROTOS + w * DIM + d];
    pr[d] = v; ps += (double)v * v;
    double s = ws[OFF_QSUM + d];
    for (int w2 = 0; w2 < WAY; ++w2) s += 5.0 * (double)ws[OFF_PROTOS + w2 * DIM + d];
    am[d] = (float)(s / 4256.0);
  }
  ps = wave_sum_d(ps);
  int lane = t & 63, wid = t >> 6;
  if (lane == 0) redd[wid] = ps;
  __syncthreads();
  // H1: neuron n = t&127, k-slice s = t>>7 (4 slices x 320)
  {
    int n = t & 127, s = t >> 7;
    float acc = 0.f;
    if (s < 2) {
      int k0 = s * 320;
#pragma unroll 8
      for (int k = 0; k < 320; ++k) acc = fmaf(pr[k0 + k], W1[(size_t)(k0 + k) * 128 + n], acc);
    } else {
      int k0 = (s - 2) * 320;
#pragma unroll 8
      for (int k = 0; k < 320; ++k) acc = fmaf(am[k0 + k], W1[(size_t)(640 + k0 + k) * 128 + n], acc);
    }
    h1p[s][n] = acc;
  }
  __syncthreads();
  if (t < 128) h1s[t] = fmaxf(h1p[0][t] + h1p[1][t] + h1p[2][t] + h1p[3][t] + b1[t], 0.f);
  __syncthreads();
  // H2: n = t&63, s = t>>6 (8 slices x 16)
  {
    int n = t & 63, s = t >> 6;
    int k0 = s * 16;
    float acc = 0.f;
#pragma unroll
    for (int k = 0; k < 16; ++k) acc = fmaf(h1s[k0 + k], W2[(size_t)(k0 + k) * 64 + n], acc);
    h2p[s][n] = acc;
  }
  __syncthreads();
  if (t < 64) {
    float a = h2p[0][t];
#pragma unroll
    for (int s = 1; s < 8; ++s) a += h2p[s][t];
    h2s[t] = fmaxf(a + b2[t], 0.f);
  }
  __syncthreads();
  if (t < 5) {
    float a = b3[t];
    for (int k = 0; k < 64; ++k) a = fmaf(h2s[k], W3[k * 5 + t], a);
    lg[t] = a;
  }
  __syncthreads();
  if (t == 0) {
    double p2 = 0.0;
    for (int i = 0; i < 8; ++i) p2 += redd[i];
    double m = lg[0];
    for (int i = 1; i < 5; ++i) m = fmax(m, (double)lg[i]);
    double se = 0.0, cv = 0.0;
    for (int i = 0; i < 5; ++i) { double e = exp((double)lg[i] - m); se += e; cv += e * 0.2 * (double)(i + 1); }
    double c = cv / se;
    ws[OFF_C + w] = (float)c;
    double sc = sqrt(c);
    double ntrue = sqrt(p2);
    double nf = fmax(ntrue, 1e-5);
    double th = tanh(sc * nf);
    double s0 = th / (sc * nf);
    double ny = fmax(s0 * ntrue, 1e-5);
    double mx = 0.999 / sc;
    if (ny > mx) s0 *= mx / ny;
    sBeta = s0;
    ((double*)(ws + OFF_X2D))[w] = s0 * s0 * p2;
  }
  __syncthreads();
  float beta = (float)sBeta;
  for (int d = t; d < DIM; d += 512) ws[OFF_XVEC + w * DIM + d] = beta * pr[d];
}

// split-K GEMM: G[w][q] += X[w]·Qm[q] over a 64-dim K chunk (grid: 32 q-tiles x 10 k-tiles)
__global__ __launch_bounds__(256) void k_gemm(const float* __restrict__ X, const float* __restrict__ Qm,
                                              float* __restrict__ G) {
  __shared__ float qs[64][132];
  __shared__ float xs[64][36];
  int q0 = blockIdx.x * 128, k0 = blockIdx.y * 64;
  int t = threadIdx.x;
  {
    int kk = t & 15, qb = t >> 4;
#pragma unroll
    for (int p = 0; p < 8; ++p) {
      int q = p * 16 + qb;
      const float4 v = *(const float4*)(Qm + (size_t)(q0 + q) * DIM + k0 + kk * 4);
      qs[kk * 4 + 0][q] = v.x; qs[kk * 4 + 1][q] = v.y; qs[kk * 4 + 2][q] = v.z; qs[kk * 4 + 3][q] = v.w;
    }
#pragma unroll
    for (int p = 0; p < 2; ++p) {
      int fi = p * 256 + t;
      int xw = fi >> 4, kk2 = fi & 15;
      const float4 v = *(const float4*)(X + (size_t)xw * DIM + k0 + kk2 * 4);
      xs[kk2 * 4 + 0][xw] = v.x; xs[kk2 * 4 + 1][xw] = v.y; xs[kk2 * 4 + 2][xw] = v.z; xs[kk2 * 4 + 3][xw] = v.w;
    }
  }
  __syncthreads();
  int qg = t & 31, wg = t >> 5;
  float acc[4][4] = {};
#pragma unroll 8
  for (int k = 0; k < 64; ++k) {
    float4 qv = *(const float4*)&qs[k][qg * 4];
    float4 xv = *(const float4*)&xs[k][wg * 4];
    acc[0][0] = fmaf(xv.x, qv.x, acc[0][0]); acc[0][1] = fmaf(xv.x, qv.y, acc[0][1]);
    acc[0][2] = fmaf(xv.x, qv.z, acc[0][2]); acc[0][3] = fmaf(xv.x, qv.w, acc[0][3]);
    acc[1][0] = fmaf(xv.y, qv.x, acc[1][0]); acc[1][1] = fmaf(xv.y, qv.y, acc[1][1]);
    acc[1][2] = fmaf(xv.y, qv.z, acc[1][2]); acc[1][3] = fmaf(xv.y, qv.w, acc[1][3]);
    acc[2][0] = fmaf(xv.z, qv.x, acc[2][0]); acc[2][1] = fmaf(xv.z, qv.y, acc[2][1]);
    acc[2][2] = fmaf(xv.z, qv.z, acc[2][2]); acc[2][3] = fmaf(xv.z, qv.w, acc[2][3]);
    acc[3][0] = fmaf(xv.w, qv.x, acc[3][0]); acc[3][1] = fmaf(xv.w, qv.y, acc[3][1]);
    acc[3][2] = fmaf(xv.w, qv.z, acc[3][2]); acc[3][3] = fmaf(xv.w, qv.w, acc[3][3]);
  }
  int wb = wg * 4, qb2 = q0 + qg * 4;
#pragma unroll
  for (int i = 0; i < 4; ++i)
#pragma unroll
    for (int j = 0; j < 4; ++j)
      atomicAdd(&G[(size_t)(wb + i) * NQ + qb2 + j], acc[i][j]);
}

__global__ __launch_bounds__(256) void k_epi1(float* ws) {
  const double* q2d = (const double*)(ws + OFF_Q2D);
  const double* x2d = (const double*)(ws + OFF_X2D);
  int gid = blockIdx.x * 256 + threadIdx.x;
  if (gid >= WAY * NQ) return;
  int w = gid >> 12, q = gid & (NQ - 1);
  double c = (double)ws[OFF_C + w];
  double d = dist_hyp(c, (double)ws[OFF_G + gid], x2d[w], q2d[q]);
  ws[OFF_DIS + gid] = (float)d;
}

// per-way: row sum S, first-10-raw-col sum U, stable top-10 (value, then index)
__global__ __launch_bounds__(256) void k_topk(float* ws, int* nidx) {
  __shared__ double sredS[4], sredU[4];
  __shared__ float wv[4]; __shared__ int wi[4];
  __shared__ int swi;
  int w = blockIdx.x, t = threadIdx.x;
  int lane = t & 63, wid = t >> 6;
  float v[16]; bool tk[16];
  double s = 0.0, u = 0.0;
#pragma unroll
  for (int i = 0; i < 16; ++i) {
    int q = i * 256 + t;
    float vv = ws[OFF_DIS + w * NQ + q];
    v[i] = vv; tk[i] = false;
    s += vv;
    if (i == 0 && t < RNEAR) u += vv;
  }
  s = wave_sum_d(s);
  u = wave_sum_d(u);
  if (lane == 0) { sredS[wid] = s; sredU[wid] = u; }
  __syncthreads();
  if (t == 0) {
    ws[OFF_S + w] = (float)(sredS[0] + sredS[1] + sredS[2] + sredS[3]);
    ws[OFF_U + w] = (float)(sredU[0] + sredU[1] + sredU[2] + sredU[3]);
  }
  for (int r = 0; r < RNEAR; ++r) {
    float lv = INFINITY; int li = 0x7fffffff;
#pragma unroll
    for (int i = 0; i < 16; ++i) {
      if (!tk[i]) {
        float vv = v[i]; int qq = i * 256 + t;
        if (vv < lv || (vv == lv && qq < li)) { lv = vv; li = qq; }
      }
    }
#pragma unroll
    for (int o = 32; o > 0; o >>= 1) {
      float ov = __shfl_down(lv, o, 64);
      int oi = __shfl_down(li, o, 64);
      if (ov < lv || (ov == lv && oi < li)) { lv = ov; li = oi; }
    }
    if (lane == 0) { wv[wid] = lv; wi[wid] = li; }
    __syncthreads();
    if (t == 0) {
      float bv = wv[0]; int bi = wi[0];
      for (int k = 1; k < 4; ++k)
        if (wv[k] < bv || (wv[k] == bv && wi[k] < bi)) { bv = wv[k]; bi = wi[k]; }
      ws[OFF_NID + w * RNEAR + r] = bv;
      nidx[w * RNEAR + r] = bi;
      swi = bi;
    }
    __syncthreads();
    if ((swi & 255) == t) tk[swi >> 8] = true;
    __syncthreads();
  }
}

// all the small per-way stats + refine MLP -> i_w, onw
__global__ __launch_bounds__(384) void k_refine(const float* __restrict__ Wr1, const float* __restrict__ br1,
                                                const float* __restrict__ Wr2, const float* __restrict__ br2,
                                                float* ws, const int* __restrict__ nidx) {
  __shared__ float rr[WAY][22];
  __shared__ float pcs[WAY][RNEAR];
  __shared__ float Ssh[WAY], Tsh[WAY];
  __shared__ float hr[WAY][RNEAR];
  int t = threadIdx.x;
  if (t < WAY * RNEAR) {
    int w = t / RNEAR, j = t - w * RNEAR;
    int q = nidx[t];
    double cs = 0.0, pc = 0.0;
    for (int w2 = 0; w2 < WAY; ++w2) {
      float dv = ws[OFF_DIS + w2 * NQ + q];
      cs += dv;
      if (w2 < w) pc += dv;
    }
    float nv = ws[OFF_NID + t];
    rr[w][j] = nv;
    rr[w][RNEAR + j] = (float)((cs - nv) / (WAY - 1));
    pcs[w][j] = (float)pc;
  }
  if (t < WAY) { Ssh[t] = ws[OFF_S + t]; Tsh[t] = Ssh[t] - ws[OFF_U + t]; }
  __syncthreads();
  if (t < WAY) {
    int w = t;
    double sn = 0.0;
    for (int j = 0; j < RNEAR; ++j) sn += rr[w][j];
    double oi = ((double)Ssh[w] - sn) / (double)(NQ - RNEAR);
    double pref = 0.0; for (int j = 0; j < w; ++j) pref += Ssh[j];
    double suf = 0.0; for (int j = w + 1; j < WAY; ++j) suf += Tsh[j];
    double spc = 0.0; for (int j = 0; j < RNEAR; ++j) spc += pcs[w][j];
    double ood = (pref - spc + suf) / ((double)(WAY - 1) * (double)(NQ - RNEAR));
    rr[w][20] = (float)oi;
    rr[w][21] = (float)ood;
  }
  __syncthreads();
  if (t < WAY * RNEAR) {
    int w = t / RNEAR, r = t - w * RNEAR;
    float a = br1[r];
    for (int k = 0; k < 22; ++k) a = fmaf(rr[w][k], Wr1[k * RNEAR + r], a);
    hr[w][r] = fmaxf(a, 0.f);
  }
  __syncthreads();
  if (t < WAY) {
    int w = t;
    double o[11];
    for (int r2 = 0; r2 < 11; ++r2) {
      float a = br2[r2];
      for (int k = 0; k < RNEAR; ++k) a = fmaf(hr[w][k], Wr2[k * 11 + r2], a);
      o[r2] = a;
    }
    double m = o[0]; for (int i = 1; i < RNEAR; ++i) m = fmax(m, o[i]);
    double se = 0.0; double e[RNEAR];
    for (int i = 0; i < RNEAR; ++i) { e[i] = exp(o[i] - m); se += e[i]; }
    for (int i = 0; i < RNEAR; ++i) ws[OFF_IW + w * RNEAR + i] = (float)(e[i] / se);
    ws[OFF_ONW + w] = (float)(1.0 / (1.0 + exp(-o[10])));
  }
}

// tmp = protos*onw + wdq*(1-onw); test_proto = expmap0(tmp); also zero G for GEMM2
__global__ __launch_bounds__(256) void k_tmp(const float* __restrict__ Qm, float* ws, const int* __restrict__ nidx) {
  __shared__ float iw_s[RNEAR];
  __shared__ int qidx[RNEAR];
  __shared__ float tmps[DIM];
  __shared__ double sred[4];
  __shared__ double gsh;
  int w = blockIdx.x, t = threadIdx.x;
  if (t < RNEAR) { iw_s[t] = ws[OFF_IW + w * RNEAR + t]; qidx[t] = nidx[w * RNEAR + t]; }
  __syncthreads();
  float onwv = ws[OFF_ONW + w];
  double ls = 0.0;
  for (int d = t; d < DIM; d += 256) {
    float wd = 0.f;
#pragma unroll
    for (int j = 0; j < RNEAR; ++j) wd = fmaf(Qm[(size_t)qidx[j] * DIM + d], iw_s[j], wd);
    float a = ws[OFF_PROTOS + w * DIM + d] * onwv + wd * (1.f - onwv);
    tmps[d] = a;
    ls += (double)a * a;
  }
  ls = wave_sum_d(ls);
  int lane = t & 63, wid = t >> 6;
  if (lane == 0) sred[wid] = ls;
  __syncthreads();
  if (t == 0) {
    double p2 = sred[0] + sred[1] + sred[2] + sred[3];
    double c = (double)ws[OFF_C + w];
    double sc = sqrt(c);
    double ntrue = sqrt(p2);
    double nf = fmax(ntrue, 1e-5);
    double th = tanh(sc * nf);
    double s0 = th / (sc * nf);
    double ny = fmax(s0 * ntrue, 1e-5);
    double mx = 0.999 / sc;
    if (ny > mx) s0 *= mx / ny;
    gsh = s0;
    ((double*)(ws + OFF_X2D))[w] = s0 * s0 * p2;
  }
  __syncthreads();
  float g = (float)gsh;
  for (int d = t; d < DIM; d += 256) ws[OFF_TP + w * DIM + d] = g * tmps[d];
  int gt = w * 256 + t;
  for (int j = gt; j < WAY * NQ; j += WAY * 256) ws[OFF_G + j] = 0.0f;
}

// final distances -> out[q][w] = -d/16, via LDS transpose for coalesced writes
__global__ __launch_bounds__(256) void k_epi2(float* ws, float* __restrict__ out) {
  __shared__ float ot[64][33];
  const double* q2d = (const double*)(ws + OFF_Q2D);
  const double* x2d = (const double*)(ws + OFF_X2D);
  int qb = blockIdx.x * 64, t = threadIdx.x;
  int w = t >> 3, q80 = (t & 7) * 8;
  double c = (double)ws[OFF_C + w];
  double u2 = x2d[w];
  for (int j = 0; j < 8; ++j) {
    int qq = q80 + j, q = qb + qq;
    double g = (double)ws[OFF_G + (size_t)w * NQ + q];
    double d = dist_hyp(c, g, u2, q2d[q]);
    ot[qq][w] = (float)(-d / 16.0);
  }
  __syncthreads();
  for (int j = 0; j < 8; ++j) {
    int l = t * 8 + j;
    int qq = l >> 5, w2 = l & 31;
    out[(size_t)(qb + qq) * WAY + w2] = ot[qq][w2];
  }
}

extern "C" void kernel_launch(void* const* d_in, const int* in_sizes, int n_in,
                              void* d_out, int out_size, void* d_ws, size_t ws_size,
                              hipStream_t stream) {
  (void)in_sizes; (void)n_in; (void)out_size; (void)ws_size;
  const float* shot = (const float*)d_in[0];
  const float* qry  = (const float*)d_in[1];
  const float* W1   = (const float*)d_in[2];
  const float* b1   = (const float*)d_in[3];
  const float* W2   = (const float*)d_in[4];
  const float* b2   = (const float*)d_in[5];
  const float* W3   = (const float*)d_in[6];
  const float* b3   = (const float*)d_in[7];
  const float* Wr1  = (const float*)d_in[8];
  const float* br1  = (const float*)d_in[9];
  const float* Wr2  = (const float*)d_in[10];
  const float* br2  = (const float*)d_in[11];
  float* ws = (float*)d_ws;
  float* out = (float*)d_out;
  int* nidx = (int*)(ws + OFF_NIDX);

  hipLaunchKernelGGL(k_zeroqs, dim3(3), dim3(256), 0, stream, ws);
  hipLaunchKernelGGL(k_q2,     dim3(1024), dim3(256), 0, stream, qry, ws);
  hipLaunchKernelGGL(k_qsum,   dim3(10, 32), dim3(64, 4), 0, stream, qry, ws);
  hipLaunchKernelGGL(k_protos, dim3(80), dim3(256), 0, stream, shot, ws);
  hipLaunchKernelGGL(k_ctrl,   dim3(32), dim3(512), 0, stream, W1, b1, W2, b2, W3, b3, ws);
  hipLaunchKernelGGL(k_gemm,   dim3(32, 10), dim3(256), 0, stream, ws + OFF_XVEC, qry, ws + OFF_G);
  hipLaunchKernelGGL(k_epi1,   dim3(512), dim3(256), 0, stream, ws);
  hipLaunchKernelGGL(k_topk,   dim3(32), dim3(256), 0, stream, ws, nidx);
  hipLaunchKernelGGL(k_refine, dim3(1), dim3(384), 0, stream, Wr1, br1, Wr2, br2, ws, nidx);
  hipLaunchKernelGGL(k_tmp,    dim3(32), dim3(256), 0, stream, qry, ws, nidx);
  hipLaunchKernelGGL(k_gemm,   dim3(32, 10), dim3(256), 0, stream, ws + OFF_TP, qry, ws + OFF_G);
  hipLaunchKernelGGL(k_epi2,   dim3(64), dim3(256), 0, stream, ws, out);
}

// Round 4
// 123.132 us; speedup vs baseline: 1.2990x; 1.1262x over previous
//
#include <hip/hip_runtime.h>
#include <math.h>

#define NSHOT 5
#define WAY 32
#define DIM 640
#define NQ 4096
#define RNEAR 10

// ---- workspace layout (float offsets) ----
constexpr int OFF_QSUM    = 0;         // 640
constexpr int OFF_PROTOS  = 640;       // 32*640
constexpr int OFF_C       = 21760;     // 32
constexpr int OFF_XVEC    = 21792;     // 32*640 (proto_p)
constexpr int OFF_G       = 42272;     // 32*4096
constexpr int OFF_DIS     = 173344;    // 32*4096
constexpr int OFF_S       = 304416;    // 32
constexpr int OFF_U       = 304448;    // 32
constexpr int OFF_NID     = 304480;    // 32*10
constexpr int OFF_IW      = 304800;    // 32*10
constexpr int OFF_ONW     = 305120;    // 32
constexpr int OFF_TP      = 305152;    // 32*640 (test_proto)
constexpr int OFF_NIDX    = 325632;    // 32*10 ints
constexpr int OFF_Q2D     = 325952;    // double[4096]
constexpr int OFF_X2D     = 334144;    // double[32]

__device__ __forceinline__ double wave_sum_d(double v) {
#pragma unroll
  for (int o = 32; o > 0; o >>= 1) v += __shfl_down(v, o, 64);
  return v;
}

__device__ __forceinline__ double dist_hyp(double c, double xdotq, double u2, double q2) {
  const double EPSd = 1e-5;
  double sc = sqrt(c);
  double nq = sqrt(q2);
  double nf = fmax(nq, EPSd);
  double th = tanh(sc * nf);
  double al = th / (sc * nf);
  double ny = fmax(al * nq, EPSd);
  double mx = 0.999 / sc;
  if (ny > mx) al *= mx / ny;
  double y2 = al * al * q2;
  double uy = -al * xdotq;
  double A = 1.0 + 2.0 * c * uy + c * y2;
  double B = 1.0 - c * u2;
  double den = fmax(1.0 + 2.0 * c * uy + c * c * u2 * y2, EPSd);
  double num2 = fmax(A * A * u2 + 2.0 * A * B * uy + B * B * y2, 0.0);
  double n = sqrt(num2) / den;
  double arg = sc * n;
  const double CLIP = (double)(1.0f - 1e-5f);
  arg = fmin(fmax(arg, 0.0), CLIP);
  return (1.0 / sc) * log((1.0 + arg) / (1.0 - arg));
}

// per-query squared norms (double) + zero G (for gemm1 atomics) + zero QSUM
__global__ __launch_bounds__(256) void k_q2(const float* __restrict__ Qm, float* ws) {
  double* q2d = (double*)(ws + OFF_Q2D);
  int wid = threadIdx.x >> 6, lane = threadIdx.x & 63;
  int row = blockIdx.x * 4 + wid;
  const float* r = Qm + (size_t)row * DIM;
  double s = 0.0;
  for (int j = lane; j < DIM; j += 64) { double v = r[j]; s += v * v; }
  s = wave_sum_d(s);
  if (lane == 0) q2d[row] = s;
  int gid = blockIdx.x * 256 + threadIdx.x;
  if (gid < WAY * NQ) ws[OFF_G + gid] = 0.0f;
  if (gid < 640) ws[OFF_QSUM + gid] = 0.0f;
}

// column sums of data_query: grid (10, 32), block 256 = 64 cols x 4 row-groups
__global__ void k_qsum(const float* __restrict__ Qm, float* ws) {
  __shared__ float red[4][64];
  int col = blockIdx.x * 64 + threadIdx.x;
  int r0 = blockIdx.y * 128 + threadIdx.y * 32;
  float s = 0.f;
  for (int r = 0; r < 32; ++r) s += Qm[(size_t)(r0 + r) * DIM + col];
  red[threadIdx.y][threadIdx.x] = s;
  __syncthreads();
  if (threadIdx.y == 0) {
    float tot = red[0][threadIdx.x] + red[1][threadIdx.x] + red[2][threadIdx.x] + red[3][threadIdx.x];
    atomicAdd(&ws[OFF_QSUM + col], tot);
  }
}

__global__ void k_protos(const float* __restrict__ shot, float* ws) {
  int i = blockIdx.x * blockDim.x + threadIdx.x;
  if (i >= WAY * DIM) return;
  int w = i / DIM, d = i - w * DIM;
  float s = 0.f;
#pragma unroll
  for (int s5 = 0; s5 < NSHOT; ++s5) s += shot[(size_t)(s5 * WAY + w) * DIM + d];
  ws[OFF_PROTOS + i] = s * 0.2f;
}

// controller MLP, split-K, 512 threads; allmean computed inline per block
__global__ __launch_bounds__(512) void k_ctrl(const float* __restrict__ W1, const float* __restrict__ b1,
                                              const float* __restrict__ W2, const float* __restrict__ b2,
                                              const float* __restrict__ W3, const float* __restrict__ b3,
                                              float* ws) {
  __shared__ float pr[DIM], am[DIM];
  __shared__ float h1p[4][128], h1s[128];
  __shared__ float h2p[8][64], h2s[64];
  __shared__ float lg[5];
  __shared__ double redd[8];
  __shared__ double sBeta;
  int w = blockIdx.x, t = threadIdx.x;
  double ps = 0.0;
  for (int d = t; d < DIM; d += 512) {
    float v = ws[OFF_PROTOS + w * DIM + d];
    pr[d] = v; ps += (double)v * v;
    double s = ws[OFF_QSUM + d];
    for (int w2 = 0; w2 < WAY; ++w2) s += 5.0 * (double)ws[OFF_PROTOS + w2 * DIM + d];
    am[d] = (float)(s / 4256.0);
  }
  ps = wave_sum_d(ps);
  int lane = t & 63, wid = t >> 6;
  if (lane == 0) redd[wid] = ps;
  __syncthreads();
  {
    int n = t & 127, s = t >> 7;
    float acc = 0.f;
    if (s < 2) {
      int k0 = s * 320;
#pragma unroll 8
      for (int k = 0; k < 320; ++k) acc = fmaf(pr[k0 + k], W1[(size_t)(k0 + k) * 128 + n], acc);
    } else {
      int k0 = (s - 2) * 320;
#pragma unroll 8
      for (int k = 0; k < 320; ++k) acc = fmaf(am[k0 + k], W1[(size_t)(640 + k0 + k) * 128 + n], acc);
    }
    h1p[s][n] = acc;
  }
  __syncthreads();
  if (t < 128) h1s[t] = fmaxf(h1p[0][t] + h1p[1][t] + h1p[2][t] + h1p[3][t] + b1[t], 0.f);
  __syncthreads();
  {
    int n = t & 63, s = t >> 6;
    int k0 = s * 16;
    float acc = 0.f;
#pragma unroll
    for (int k = 0; k < 16; ++k) acc = fmaf(h1s[k0 + k], W2[(size_t)(k0 + k) * 64 + n], acc);
    h2p[s][n] = acc;
  }
  __syncthreads();
  if (t < 64) {
    float a = h2p[0][t];
#pragma unroll
    for (int s = 1; s < 8; ++s) a += h2p[s][t];
    h2s[t] = fmaxf(a + b2[t], 0.f);
  }
  __syncthreads();
  if (t < 5) {
    float a = b3[t];
    for (int k = 0; k < 64; ++k) a = fmaf(h2s[k], W3[k * 5 + t], a);
    lg[t] = a;
  }
  __syncthreads();
  if (t == 0) {
    double p2 = 0.0;
    for (int i = 0; i < 8; ++i) p2 += redd[i];
    double m = lg[0];
    for (int i = 1; i < 5; ++i) m = fmax(m, (double)lg[i]);
    double se = 0.0, cv = 0.0;
    for (int i = 0; i < 5; ++i) { double e = exp((double)lg[i] - m); se += e; cv += e * 0.2 * (double)(i + 1); }
    double c = cv / se;
    ws[OFF_C + w] = (float)c;
    double sc = sqrt(c);
    double ntrue = sqrt(p2);
    double nf = fmax(ntrue, 1e-5);
    double th = tanh(sc * nf);
    double s0 = th / (sc * nf);
    double ny = fmax(s0 * ntrue, 1e-5);
    double mx = 0.999 / sc;
    if (ny > mx) s0 *= mx / ny;
    sBeta = s0;
    ((double*)(ws + OFF_X2D))[w] = s0 * s0 * p2;
  }
  __syncthreads();
  float beta = (float)sBeta;
  for (int d = t; d < DIM; d += 512) ws[OFF_XVEC + w * DIM + d] = beta * pr[d];
}

// split-K GEMM: G[w][q] += X[w]·Qm[q] over a 64-dim K chunk (grid: 32 q-tiles x 10 k-tiles)
__global__ __launch_bounds__(256) void k_gemm(const float* __restrict__ X, const float* __restrict__ Qm,
                                              float* __restrict__ G) {
  __shared__ float qs[64][132];
  __shared__ float xs[64][36];
  int q0 = blockIdx.x * 128, k0 = blockIdx.y * 64;
  int t = threadIdx.x;
  {
    int kk = t & 15, qb = t >> 4;
#pragma unroll
    for (int p = 0; p < 8; ++p) {
      int q = p * 16 + qb;
      const float4 v = *(const float4*)(Qm + (size_t)(q0 + q) * DIM + k0 + kk * 4);
      qs[kk * 4 + 0][q] = v.x; qs[kk * 4 + 1][q] = v.y; qs[kk * 4 + 2][q] = v.z; qs[kk * 4 + 3][q] = v.w;
    }
#pragma unroll
    for (int p = 0; p < 2; ++p) {
      int fi = p * 256 + t;
      int xw = fi >> 4, kk2 = fi & 15;
      const float4 v = *(const float4*)(X + (size_t)xw * DIM + k0 + kk2 * 4);
      xs[kk2 * 4 + 0][xw] = v.x; xs[kk2 * 4 + 1][xw] = v.y; xs[kk2 * 4 + 2][xw] = v.z; xs[kk2 * 4 + 3][xw] = v.w;
    }
  }
  __syncthreads();
  int qg = t & 31, wg = t >> 5;
  float acc[4][4] = {};
#pragma unroll 8
  for (int k = 0; k < 64; ++k) {
    float4 qv = *(const float4*)&qs[k][qg * 4];
    float4 xv = *(const float4*)&xs[k][wg * 4];
    acc[0][0] = fmaf(xv.x, qv.x, acc[0][0]); acc[0][1] = fmaf(xv.x, qv.y, acc[0][1]);
    acc[0][2] = fmaf(xv.x, qv.z, acc[0][2]); acc[0][3] = fmaf(xv.x, qv.w, acc[0][3]);
    acc[1][0] = fmaf(xv.y, qv.x, acc[1][0]); acc[1][1] = fmaf(xv.y, qv.y, acc[1][1]);
    acc[1][2] = fmaf(xv.y, qv.z, acc[1][2]); acc[1][3] = fmaf(xv.y, qv.w, acc[1][3]);
    acc[2][0] = fmaf(xv.z, qv.x, acc[2][0]); acc[2][1] = fmaf(xv.z, qv.y, acc[2][1]);
    acc[2][2] = fmaf(xv.z, qv.z, acc[2][2]); acc[2][3] = fmaf(xv.z, qv.w, acc[2][3]);
    acc[3][0] = fmaf(xv.w, qv.x, acc[3][0]); acc[3][1] = fmaf(xv.w, qv.y, acc[3][1]);
    acc[3][2] = fmaf(xv.w, qv.z, acc[3][2]); acc[3][3] = fmaf(xv.w, qv.w, acc[3][3]);
  }
  int wb = wg * 4, qb2 = q0 + qg * 4;
#pragma unroll
  for (int i = 0; i < 4; ++i)
#pragma unroll
    for (int j = 0; j < 4; ++j)
      atomicAdd(&G[(size_t)(wb + i) * NQ + qb2 + j], acc[i][j]);
}

__global__ __launch_bounds__(256) void k_epi1(float* ws) {
  const double* q2d = (const double*)(ws + OFF_Q2D);
  const double* x2d = (const double*)(ws + OFF_X2D);
  int gid = blockIdx.x * 256 + threadIdx.x;
  if (gid >= WAY * NQ) return;
  int w = gid >> 12, q = gid & (NQ - 1);
  double c = (double)ws[OFF_C + w];
  double d = dist_hyp(c, (double)ws[OFF_G + gid], x2d[w], q2d[q]);
  ws[OFF_DIS + gid] = (float)d;
}

// per-way: row sum S, first-10-raw-col sum U, stable top-10 (value, then index).
// All state in registers: 4 named values + 4-bit taken mask. 1024 threads.
__global__ __launch_bounds__(1024) void k_topk(float* ws, int* nidx) {
  __shared__ double sredS[16], sredU[16];
  __shared__ float wv[16]; __shared__ int wi[16];
  __shared__ int swi;
  int w = blockIdx.x, t = threadIdx.x;
  int lane = t & 63, wid = t >> 6;   // 16 waves
  const float* base = ws + OFF_DIS + (size_t)w * NQ;
  float v0 = base[t], v1 = base[1024 + t], v2 = base[2048 + t], v3 = base[3072 + t];
  unsigned tk = 0;
  double s = (double)v0 + (double)v1 + (double)v2 + (double)v3;
  double u = (t < RNEAR) ? (double)v0 : 0.0;     // q==t for the first chunk
  s = wave_sum_d(s);
  u = wave_sum_d(u);
  if (lane == 0) { sredS[wid] = s; sredU[wid] = u; }
  __syncthreads();
  if (t == 0) {
    double S = 0.0, U = 0.0;
    for (int k = 0; k < 16; ++k) { S += sredS[k]; U += sredU[k]; }
    ws[OFF_S + w] = (float)S;
    ws[OFF_U + w] = (float)U;
  }
  for (int r = 0; r < RNEAR; ++r) {
    float lv = INFINITY; int li = 0x7fffffff;
    if (!(tk & 1u) && (v0 < lv || (v0 == lv && t < li)))          { lv = v0; li = t; }
    if (!(tk & 2u) && (v1 < lv || (v1 == lv && 1024 + t < li)))   { lv = v1; li = 1024 + t; }
    if (!(tk & 4u) && (v2 < lv || (v2 == lv && 2048 + t < li)))   { lv = v2; li = 2048 + t; }
    if (!(tk & 8u) && (v3 < lv || (v3 == lv && 3072 + t < li)))   { lv = v3; li = 3072 + t; }
#pragma unroll
    for (int o = 32; o > 0; o >>= 1) {
      float ov = __shfl_down(lv, o, 64);
      int oi = __shfl_down(li, o, 64);
      if (ov < lv || (ov == lv && oi < li)) { lv = ov; li = oi; }
    }
    if (lane == 0) { wv[wid] = lv; wi[wid] = li; }
    __syncthreads();
    if (t < 64) {
      float bv = (lane < 16) ? wv[lane] : INFINITY;
      int bi = (lane < 16) ? wi[lane] : 0x7fffffff;
#pragma unroll
      for (int o = 8; o > 0; o >>= 1) {
        float ov = __shfl_down(bv, o, 64);
        int oi = __shfl_down(bi, o, 64);
        if (ov < bv || (ov == bv && oi < bi)) { bv = ov; bi = oi; }
      }
      if (lane == 0) {
        ws[OFF_NID + w * RNEAR + r] = bv;
        nidx[w * RNEAR + r] = bi;
        swi = bi;
      }
    }
    __syncthreads();
    int sw = swi;
    if ((sw & 1023) == t) tk |= 1u << (sw >> 10);
  }
}

// all the small per-way stats + refine MLP -> i_w, onw
__global__ __launch_bounds__(384) void k_refine(const float* __restrict__ Wr1, const float* __restrict__ br1,
                                                const float* __restrict__ Wr2, const float* __restrict__ br2,
                                                float* ws, const int* __restrict__ nidx) {
  __shared__ float rr[WAY][22];
  __shared__ float pcs[WAY][RNEAR];
  __shared__ float Ssh[WAY], Tsh[WAY];
  __shared__ float hr[WAY][RNEAR];
  int t = threadIdx.x;
  if (t < WAY * RNEAR) {
    int w = t / RNEAR, j = t - w * RNEAR;
    int q = nidx[t];
    double cs = 0.0, pc = 0.0;
    for (int w2 = 0; w2 < WAY; ++w2) {
      float dv = ws[OFF_DIS + w2 * NQ + q];
      cs += dv;
      if (w2 < w) pc += dv;
    }
    float nv = ws[OFF_NID + t];
    rr[w][j] = nv;
    rr[w][RNEAR + j] = (float)((cs - nv) / (WAY - 1));
    pcs[w][j] = (float)pc;
  }
  if (t < WAY) { Ssh[t] = ws[OFF_S + t]; Tsh[t] = Ssh[t] - ws[OFF_U + t]; }
  __syncthreads();
  if (t < WAY) {
    int w = t;
    double sn = 0.0;
    for (int j = 0; j < RNEAR; ++j) sn += rr[w][j];
    double oi = ((double)Ssh[w] - sn) / (double)(NQ - RNEAR);
    double pref = 0.0; for (int j = 0; j < w; ++j) pref += Ssh[j];
    double suf = 0.0; for (int j = w + 1; j < WAY; ++j) suf += Tsh[j];
    double spc = 0.0; for (int j = 0; j < RNEAR; ++j) spc += pcs[w][j];
    double ood = (pref - spc + suf) / ((double)(WAY - 1) * (double)(NQ - RNEAR));
    rr[w][20] = (float)oi;
    rr[w][21] = (float)ood;
  }
  __syncthreads();
  if (t < WAY * RNEAR) {
    int w = t / RNEAR, r = t - w * RNEAR;
    float a = br1[r];
    for (int k = 0; k < 22; ++k) a = fmaf(rr[w][k], Wr1[k * RNEAR + r], a);
    hr[w][r] = fmaxf(a, 0.f);
  }
  __syncthreads();
  if (t < WAY) {
    int w = t;
    double o[11];
    for (int r2 = 0; r2 < 11; ++r2) {
      float a = br2[r2];
      for (int k = 0; k < RNEAR; ++k) a = fmaf(hr[w][k], Wr2[k * 11 + r2], a);
      o[r2] = a;
    }
    double m = o[0]; for (int i = 1; i < RNEAR; ++i) m = fmax(m, o[i]);
    double se = 0.0; double e[RNEAR];
    for (int i = 0; i < RNEAR; ++i) { e[i] = exp(o[i] - m); se += e[i]; }
    for (int i = 0; i < RNEAR; ++i) ws[OFF_IW + w * RNEAR + i] = (float)(e[i] / se);
    ws[OFF_ONW + w] = (float)(1.0 / (1.0 + exp(-o[10])));
  }
}

// tmp = protos*onw + wdq*(1-onw); test_proto = expmap0(tmp); also zero G for GEMM2
__global__ __launch_bounds__(256) void k_tmp(const float* __restrict__ Qm, float* ws, const int* __restrict__ nidx) {
  __shared__ float iw_s[RNEAR];
  __shared__ int qidx[RNEAR];
  __shared__ float tmps[DIM];
  __shared__ double sred[4];
  __shared__ double gsh;
  int w = blockIdx.x, t = threadIdx.x;
  if (t < RNEAR) { iw_s[t] = ws[OFF_IW + w * RNEAR + t]; qidx[t] = nidx[w * RNEAR + t]; }
  __syncthreads();
  float onwv = ws[OFF_ONW + w];
  double ls = 0.0;
  for (int d = t; d < DIM; d += 256) {
    float wd = 0.f;
#pragma unroll
    for (int j = 0; j < RNEAR; ++j) wd = fmaf(Qm[(size_t)qidx[j] * DIM + d], iw_s[j], wd);
    float a = ws[OFF_PROTOS + w * DIM + d] * onwv + wd * (1.f - onwv);
    tmps[d] = a;
    ls += (double)a * a;
  }
  ls = wave_sum_d(ls);
  int lane = t & 63, wid = t >> 6;
  if (lane == 0) sred[wid] = ls;
  __syncthreads();
  if (t == 0) {
    double p2 = sred[0] + sred[1] + sred[2] + sred[3];
    double c = (double)ws[OFF_C + w];
    double sc = sqrt(c);
    double ntrue = sqrt(p2);
    double nf = fmax(ntrue, 1e-5);
    double th = tanh(sc * nf);
    double s0 = th / (sc * nf);
    double ny = fmax(s0 * ntrue, 1e-5);
    double mx = 0.999 / sc;
    if (ny > mx) s0 *= mx / ny;
    gsh = s0;
    ((double*)(ws + OFF_X2D))[w] = s0 * s0 * p2;
  }
  __syncthreads();
  float g = (float)gsh;
  for (int d = t; d < DIM; d += 256) ws[OFF_TP + w * DIM + d] = g * tmps[d];
  int gt = w * 256 + t;
  for (int j = gt; j < WAY * NQ; j += WAY * 256) ws[OFF_G + j] = 0.0f;
}

// final distances -> out[q][w] = -d/16, via LDS transpose for coalesced writes
__global__ __launch_bounds__(256) void k_epi2(float* ws, float* __restrict__ out) {
  __shared__ float ot[64][33];
  const double* q2d = (const double*)(ws + OFF_Q2D);
  const double* x2d = (const double*)(ws + OFF_X2D);
  int qb = blockIdx.x * 64, t = threadIdx.x;
  int w = t >> 3, q80 = (t & 7) * 8;
  double c = (double)ws[OFF_C + w];
  double u2 = x2d[w];
  for (int j = 0; j < 8; ++j) {
    int qq = q80 + j, q = qb + qq;
    double g = (double)ws[OFF_G + (size_t)w * NQ + q];
    double d = dist_hyp(c, g, u2, q2d[q]);
    ot[qq][w] = (float)(-d / 16.0);
  }
  __syncthreads();
  for (int j = 0; j < 8; ++j) {
    int l = t * 8 + j;
    int qq = l >> 5, w2 = l & 31;
    out[(size_t)(qb + qq) * WAY + w2] = ot[qq][w2];
  }
}

extern "C" void kernel_launch(void* const* d_in, const int* in_sizes, int n_in,
                              void* d_out, int out_size, void* d_ws, size_t ws_size,
                              hipStream_t stream) {
  (void)in_sizes; (void)n_in; (void)out_size; (void)ws_size;
  const float* shot = (const float*)d_in[0];
  const float* qry  = (const float*)d_in[1];
  const float* W1   = (const float*)d_in[2];
  const float* b1   = (const float*)d_in[3];
  const float* W2   = (const float*)d_in[4];
  const float* b2   = (const float*)d_in[5];
  const float* W3   = (const float*)d_in[6];
  const float* b3   = (const float*)d_in[7];
  const float* Wr1  = (const float*)d_in[8];
  const float* br1  = (const float*)d_in[9];
  const float* Wr2  = (const float*)d_in[10];
  const float* br2  = (const float*)d_in[11];
  float* ws = (float*)d_ws;
  float* out = (float*)d_out;
  int* nidx = (int*)(ws + OFF_NIDX);

  hipLaunchKernelGGL(k_q2,     dim3(1024), dim3(256), 0, stream, qry, ws);
  hipLaunchKernelGGL(k_qsum,   dim3(10, 32), dim3(64, 4), 0, stream, qry, ws);
  hipLaunchKernelGGL(k_protos, dim3(80), dim3(256), 0, stream, shot, ws);
  hipLaunchKernelGGL(k_ctrl,   dim3(32), dim3(512), 0, stream, W1, b1, W2, b2, W3, b3, ws);
  hipLaunchKernelGGL(k_gemm,   dim3(32, 10), dim3(256), 0, stream, ws + OFF_XVEC, qry, ws + OFF_G);
  hipLaunchKernelGGL(k_epi1,   dim3(512), dim3(256), 0, stream, ws);
  hipLaunchKernelGGL(k_topk,   dim3(32), dim3(1024), 0, stream, ws, nidx);
  hipLaunchKernelGGL(k_refine, dim3(1), dim3(384), 0, stream, Wr1, br1, Wr2, br2, ws, nidx);
  hipLaunchKernelGGL(k_tmp,    dim3(32), dim3(256), 0, stream, qry, ws, nidx);
  hipLaunchKernelGGL(k_gemm,   dim3(32, 10), dim3(256), 0, stream, ws + OFF_TP, qry, ws + OFF_G);
  hipLaunchKernelGGL(k_epi2,   dim3(64), dim3(256), 0, stream, ws, out);
}